// Round 1
// 806.789 us; speedup vs baseline: 1.1191x; 1.1191x over previous
//
#include <hip/hip_runtime.h>

// ConvTP: e3nn-style tensor product message passing + segment sum.
// N_NODES=50000, N_EDGES=800000, MUL=32
// inputs: node_features (50000,128) f32, edge_angular (800000,4) f32,
//         edge_index (800000,2) int32, tp_weights (800000,160) f32
// output: (50000, 224) f32
//
// R1: atomic-bound (2.32ms). R2: CSR-by-dst build + per-node wave gather (903us).
// R3 (this): (a) replace single-block Hillis-Steele scan (1 CU, ~980 barriers)
// with a 3-kernel block scan; (b) unroll gather 2 edges/stream for MLP;
// (c) nontemporal loads on the 512MB streaming tp_weights + edge_angular so
// the reusable 25.6MB node_features gather set stays L2/L3 resident.

#define IN_DIM 128
#define W_DIM 160
#define OUT_DIM 224

typedef float vf4 __attribute__((ext_vector_type(4)));

__device__ __forceinline__ float elem(const float4& v, int i) {
    return ((const float*)&v)[i];
}

// ---------- Phase 1: histogram of dst ----------
__global__ void __launch_bounds__(256) hist_dst(
    const int2* __restrict__ eidx2, int* __restrict__ counts, int n_edges)
{
    int e = blockIdx.x * blockDim.x + threadIdx.x;
    if (e >= n_edges) return;
    atomicAdd(counts + eidx2[e].y, 1);
}

// ---------- Phase 2a: per-block (256-elem) sums ----------
__global__ void __launch_bounds__(256) block_sums(
    const int* __restrict__ counts, int* __restrict__ bsums, int n)
{
    int idx = blockIdx.x * 256 + threadIdx.x;
    int x = (idx < n) ? counts[idx] : 0;
    #pragma unroll
    for (int off = 1; off < 64; off <<= 1) x += __shfl_xor(x, off);
    __shared__ int ws[4];
    if ((threadIdx.x & 63) == 0) ws[threadIdx.x >> 6] = x;
    __syncthreads();
    if (threadIdx.x == 0) bsums[blockIdx.x] = ws[0] + ws[1] + ws[2] + ws[3];
}

// ---------- Phase 2b: exclusive scan of block sums (1 block, 256 thr) ----------
__global__ void __launch_bounds__(256) scan_block_sums(
    int* __restrict__ bsums, int* __restrict__ total_out, int nb)
{
    __shared__ int wsum[4];
    __shared__ int carry_s;
    int tid = threadIdx.x;
    int lane = tid & 63, wid = tid >> 6;
    if (tid == 0) carry_s = 0;
    __syncthreads();

    for (int base = 0; base < nb; base += 256) {
        int idx = base + tid;
        int x = (idx < nb) ? bsums[idx] : 0;
        int incl = x;
        #pragma unroll
        for (int off = 1; off < 64; off <<= 1) {
            int v = __shfl_up(incl, off);
            if (lane >= off) incl += v;
        }
        if (lane == 63) wsum[wid] = incl;
        __syncthreads();
        int wpre = 0;
        #pragma unroll
        for (int k = 0; k < 4; ++k) if (k < wid) wpre += wsum[k];
        int carry = carry_s;
        int excl = incl - x + wpre + carry;
        if (idx < nb) bsums[idx] = excl;
        __syncthreads();                 // all reads of carry_s/wsum done
        if (tid == 255) carry_s = carry + wpre + incl;   // += chunk total
        __syncthreads();
    }
    if (tid == 0) *total_out = carry_s;  // offsets[n] = total edges
}

// ---------- Phase 2c: finalize exclusive offsets in place + cursor copy ----------
__global__ void __launch_bounds__(256) scan_final(
    int* __restrict__ counts, int* __restrict__ cursor,
    const int* __restrict__ bsums, int n)
{
    int idx = blockIdx.x * 256 + threadIdx.x;
    int x = (idx < n) ? counts[idx] : 0;
    int lane = threadIdx.x & 63, wid = threadIdx.x >> 6;
    int incl = x;
    #pragma unroll
    for (int off = 1; off < 64; off <<= 1) {
        int v = __shfl_up(incl, off);
        if (lane >= off) incl += v;
    }
    __shared__ int wsum[4];
    if (lane == 63) wsum[wid] = incl;
    __syncthreads();
    int wpre = 0;
    #pragma unroll
    for (int k = 0; k < 4; ++k) if (k < wid) wpre += wsum[k];
    int excl = incl - x + wpre + bsums[blockIdx.x];
    if (idx < n) {
        counts[idx] = excl;
        cursor[idx] = excl;
    }
}

// ---------- Phase 3: scatter (edge, src) pairs grouped by dst ----------
__global__ void __launch_bounds__(256) scatter_edges(
    const int2* __restrict__ eidx2, int* __restrict__ cursor,
    int2* __restrict__ pairs, int n_edges)
{
    int e = blockIdx.x * blockDim.x + threadIdx.x;
    if (e >= n_edges) return;
    int2 sd = eidx2[e];
    int pos = atomicAdd(cursor + sd.y, 1);
    pairs[pos] = make_int2(e, sd.x);
}

// ---------- Phase 4: gather — one wave per node, lane&31 = channel ----------
__global__ void __launch_bounds__(256) gather_nodes(
    const float* __restrict__ nf,
    const float* __restrict__ ang,
    const float* __restrict__ w,
    const int*  __restrict__ offsets,
    const int2* __restrict__ pairs,
    float* __restrict__ out,
    int n_nodes)
{
    const float INV_SQRT3 = 0.5773502691896258f;
    const float INV_SQRT2 = 0.7071067811865476f;

    int gtid = blockIdx.x * blockDim.x + threadIdx.x;
    int node = gtid >> 6;          // one 64-lane wave per node
    if (node >= n_nodes) return;
    int lane = threadIdx.x & 63;
    int c    = lane & 31;          // channel
    int half = lane >> 5;          // two edge streams per wave

    int start = offsets[node];
    int end   = offsets[node + 1];

    float a0 = 0.f, a1 = 0.f, a2 = 0.f, a3 = 0.f, a4 = 0.f, a5 = 0.f, a6 = 0.f;

    auto body = [&](int2 p) {
        int e = p.x, s = p.y;
        vf4 y = __builtin_nontemporal_load((const vf4*)(ang + 4 * (size_t)e));
        const float* hp = nf + (size_t)s * IN_DIM + c;
        float h0 = hp[0];
        float ha = hp[32];
        float hb = hp[64];
        float hc = hp[96];
        const float* wp = w + (size_t)e * W_DIM + c;
        float w0 = __builtin_nontemporal_load(wp);
        float w1 = __builtin_nontemporal_load(wp + 32);
        float w2 = __builtin_nontemporal_load(wp + 64);
        float w3 = __builtin_nontemporal_load(wp + 96);
        float w4 = __builtin_nontemporal_load(wp + 128);

        float dot = ha * y[1] + hb * y[2] + hc * y[3];
        a0 += w0 * h0 * y[0] + w3 * (INV_SQRT3 * dot);
        a1 += w1 * h0 * y[1] + w2 * ha * y[0];
        a2 += w1 * h0 * y[2] + w2 * hb * y[0];
        a3 += w1 * h0 * y[3] + w2 * hc * y[0];
        float w4s = w4 * INV_SQRT2;
        a4 += w4s * (hb * y[3] - hc * y[2]);
        a5 += w4s * (hc * y[1] - ha * y[3]);
        a6 += w4s * (ha * y[2] - hb * y[1]);
    };

    int i = start + half;
    // 2-edge unrolled main loop: both edges' loads are independent -> 2x MLP
    for (; i + 2 < end; i += 4) {
        int2 pa = pairs[i];
        int2 pb = pairs[i + 2];
        body(pa);
        body(pb);
    }
    if (i < end) body(pairs[i]);

    // combine the two half-wave edge streams
    a0 += __shfl_xor(a0, 32);
    a1 += __shfl_xor(a1, 32);
    a2 += __shfl_xor(a2, 32);
    a3 += __shfl_xor(a3, 32);
    a4 += __shfl_xor(a4, 32);
    a5 += __shfl_xor(a5, 32);
    a6 += __shfl_xor(a6, 32);

    if (half == 0) {
        float* op = out + (size_t)node * OUT_DIM + c;
        __builtin_nontemporal_store(a0, op);
        __builtin_nontemporal_store(a1, op + 32);
        __builtin_nontemporal_store(a2, op + 64);
        __builtin_nontemporal_store(a3, op + 96);
        __builtin_nontemporal_store(a4, op + 128);
        __builtin_nontemporal_store(a5, op + 160);
        __builtin_nontemporal_store(a6, op + 192);
    }
}

// ---------- Fallback (R1 atomic path) if ws too small ----------
__global__ void __launch_bounds__(256) conv_tp_edges_atomic(
    const float* __restrict__ nf,
    const float* __restrict__ ang,
    const int*   __restrict__ eidx,
    const float* __restrict__ w,
    float* __restrict__ out,
    int n_edges)
{
    const float INV_SQRT3 = 0.5773502691896258f;
    const float INV_SQRT2 = 0.7071067811865476f;

    int tid = blockIdx.x * blockDim.x + threadIdx.x;
    int e = tid >> 3;
    int t = tid & 7;
    if (e >= n_edges) return;

    int src = eidx[2 * e];
    int dst = eidx[2 * e + 1];
    float4 y = *(const float4*)(ang + 4 * (size_t)e);

    const float* hp = nf + (size_t)src * IN_DIM + 4 * t;
    float4 h0  = *(const float4*)(hp);
    float4 h1a = *(const float4*)(hp + 32);
    float4 h1b = *(const float4*)(hp + 64);
    float4 h1c = *(const float4*)(hp + 96);

    const float* wp = w + (size_t)e * W_DIM + 4 * t;
    float4 w0 = *(const float4*)(wp);
    float4 w1 = *(const float4*)(wp + 32);
    float4 w2 = *(const float4*)(wp + 64);
    float4 w3 = *(const float4*)(wp + 96);
    float4 w4 = *(const float4*)(wp + 128);

    float* op = out + (size_t)dst * OUT_DIM + 4 * t;

    #pragma unroll
    for (int i = 0; i < 4; ++i) {
        float h0c = elem(h0, i), ha = elem(h1a, i), hb = elem(h1b, i), hc = elem(h1c, i);
        float dot = ha * y.y + hb * y.z + hc * y.w;
        atomicAdd(op + i, elem(w0, i) * h0c * y.x + elem(w3, i) * (INV_SQRT3 * dot));
        float w1c = elem(w1, i), w2c = elem(w2, i);
        atomicAdd(op + 32 + i, w1c * h0c * y.y + w2c * ha * y.x);
        atomicAdd(op + 64 + i, w1c * h0c * y.z + w2c * hb * y.x);
        atomicAdd(op + 96 + i, w1c * h0c * y.w + w2c * hc * y.x);
        float w4c = elem(w4, i) * INV_SQRT2;
        atomicAdd(op + 128 + i, w4c * (hb * y.w - hc * y.z));
        atomicAdd(op + 160 + i, w4c * (hc * y.y - ha * y.w));
        atomicAdd(op + 192 + i, w4c * (ha * y.z - hb * y.y));
    }
}

extern "C" void kernel_launch(void* const* d_in, const int* in_sizes, int n_in,
                              void* d_out, int out_size, void* d_ws, size_t ws_size,
                              hipStream_t stream) {
    const float* nf   = (const float*)d_in[0];
    const float* ang  = (const float*)d_in[1];
    const int*   eidx = (const int*)d_in[2];
    const float* w    = (const float*)d_in[3];
    float* out = (float*)d_out;

    int n_edges = in_sizes[2] / 2;
    int n_nodes = out_size / OUT_DIM;
    int nb = (n_nodes + 255) / 256;   // scan blocks

    // ws layout (ints): counts/offsets[n_nodes+1] | cursor[n_nodes] | bsums[nb]
    //                   | pad | pairs int2[n_edges]
    size_t off_counts = 0;
    size_t off_cursor = off_counts + (size_t)(n_nodes + 1);
    size_t off_bsums  = off_cursor + (size_t)n_nodes;
    size_t off_pairs  = (off_bsums + (size_t)nb + 1) & ~(size_t)1;  // 8B align
    size_t ints_needed = off_pairs + 2 * (size_t)n_edges;
    size_t bytes_needed = ints_needed * sizeof(int);

    if (ws_size < bytes_needed) {
        // fallback: atomic path (correct, slower)
        hipMemsetAsync(d_out, 0, (size_t)out_size * sizeof(float), stream);
        int threads_total = n_edges * 8;
        int grid = (threads_total + 255) / 256;
        conv_tp_edges_atomic<<<grid, 256, 0, stream>>>(nf, ang, eidx, w, out, n_edges);
        return;
    }

    int* counts  = (int*)d_ws + off_counts;
    int* cursor  = (int*)d_ws + off_cursor;
    int* bsums   = (int*)d_ws + off_bsums;
    int2* pairs  = (int2*)((int*)d_ws + off_pairs);

    hipMemsetAsync(counts, 0, (size_t)(n_nodes + 1) * sizeof(int), stream);

    int grid_e = (n_edges + 255) / 256;
    hist_dst<<<grid_e, 256, 0, stream>>>((const int2*)eidx, counts, n_edges);
    block_sums<<<nb, 256, 0, stream>>>(counts, bsums, n_nodes);
    scan_block_sums<<<1, 256, 0, stream>>>(bsums, counts + n_nodes, nb);
    scan_final<<<nb, 256, 0, stream>>>(counts, cursor, bsums, n_nodes);
    scatter_edges<<<grid_e, 256, 0, stream>>>((const int2*)eidx, cursor, pairs, n_edges);

    int threads_total = n_nodes * 64;           // one wave per node
    int grid_g = (threads_total + 255) / 256;
    gather_nodes<<<grid_g, 256, 0, stream>>>(nf, ang, w, counts, pairs, out, n_nodes);
}

// Round 2
// 796.616 us; speedup vs baseline: 1.1334x; 1.0128x over previous
//
#include <hip/hip_runtime.h>

// ConvTP: e3nn-style tensor product message passing + segment sum.
// N_NODES=50000, N_EDGES=800000, MUL=32
// inputs: node_features (50000,128) f32, edge_angular (800000,4) f32,
//         edge_index (800000,2) int32, tp_weights (800000,160) f32
// output: (50000, 224) f32
//
// R1: atomic-bound (2.32ms). R2: CSR-by-dst + per-node wave gather (903us).
// R3: block-scan instead of single-block scan (807us).
// R4 (this): gather is latency-bound (w loads are true HBM misses ~900cy;
// poison fill evicts L3 each iter). (a) contiguous half-split per wave so
// each half-wave loads 2 pairs per dwordx4; (b) explicit 2x2 software
// pipeline (issue next 2 edges' loads before computing current 2) ->
// guaranteed ~4 edges / ~40 loads in flight per wave; (c) dual accumulators;
// (d) int4 2-edges-per-thread hist + scatter.

#define IN_DIM 128
#define W_DIM 160
#define OUT_DIM 224

typedef float vf4 __attribute__((ext_vector_type(4)));
typedef int   vi4 __attribute__((ext_vector_type(4), aligned(8)));  // 8B-aligned int4 load

__device__ __forceinline__ float elem(const float4& v, int i) {
    return ((const float*)&v)[i];
}

// ---------- Phase 1: histogram of dst (2 edges/thread) ----------
__global__ void __launch_bounds__(256) hist_dst(
    const int* __restrict__ eidx, int* __restrict__ counts, int n_edges)
{
    int t = blockIdx.x * blockDim.x + threadIdx.x;
    int e0 = 2 * t;
    if (e0 >= n_edges) return;
    if (e0 + 1 < n_edges) {
        int4 q = *(const int4*)(eidx + 4 * (size_t)t);   // (src0,dst0,src1,dst1)
        atomicAdd(counts + q.y, 1);
        atomicAdd(counts + q.w, 1);
    } else {
        atomicAdd(counts + eidx[2 * e0 + 1], 1);
    }
}

// ---------- Phase 2a: per-block (256-elem) sums ----------
__global__ void __launch_bounds__(256) block_sums(
    const int* __restrict__ counts, int* __restrict__ bsums, int n)
{
    int idx = blockIdx.x * 256 + threadIdx.x;
    int x = (idx < n) ? counts[idx] : 0;
    #pragma unroll
    for (int off = 1; off < 64; off <<= 1) x += __shfl_xor(x, off);
    __shared__ int ws[4];
    if ((threadIdx.x & 63) == 0) ws[threadIdx.x >> 6] = x;
    __syncthreads();
    if (threadIdx.x == 0) bsums[blockIdx.x] = ws[0] + ws[1] + ws[2] + ws[3];
}

// ---------- Phase 2b: exclusive scan of block sums (1 block, 256 thr) ----------
__global__ void __launch_bounds__(256) scan_block_sums(
    int* __restrict__ bsums, int* __restrict__ total_out, int nb)
{
    __shared__ int wsum[4];
    __shared__ int carry_s;
    int tid = threadIdx.x;
    int lane = tid & 63, wid = tid >> 6;
    if (tid == 0) carry_s = 0;
    __syncthreads();

    for (int base = 0; base < nb; base += 256) {
        int idx = base + tid;
        int x = (idx < nb) ? bsums[idx] : 0;
        int incl = x;
        #pragma unroll
        for (int off = 1; off < 64; off <<= 1) {
            int v = __shfl_up(incl, off);
            if (lane >= off) incl += v;
        }
        if (lane == 63) wsum[wid] = incl;
        __syncthreads();
        int wpre = 0;
        #pragma unroll
        for (int k = 0; k < 4; ++k) if (k < wid) wpre += wsum[k];
        int carry = carry_s;
        int excl = incl - x + wpre + carry;
        if (idx < nb) bsums[idx] = excl;
        __syncthreads();                 // all reads of carry_s/wsum done
        if (tid == 255) carry_s = carry + wpre + incl;   // += chunk total
        __syncthreads();
    }
    if (tid == 0) *total_out = carry_s;  // offsets[n] = total edges
}

// ---------- Phase 2c: finalize exclusive offsets in place + cursor copy ----------
__global__ void __launch_bounds__(256) scan_final(
    int* __restrict__ counts, int* __restrict__ cursor,
    const int* __restrict__ bsums, int n)
{
    int idx = blockIdx.x * 256 + threadIdx.x;
    int x = (idx < n) ? counts[idx] : 0;
    int lane = threadIdx.x & 63, wid = threadIdx.x >> 6;
    int incl = x;
    #pragma unroll
    for (int off = 1; off < 64; off <<= 1) {
        int v = __shfl_up(incl, off);
        if (lane >= off) incl += v;
    }
    __shared__ int wsum[4];
    if (lane == 63) wsum[wid] = incl;
    __syncthreads();
    int wpre = 0;
    #pragma unroll
    for (int k = 0; k < 4; ++k) if (k < wid) wpre += wsum[k];
    int excl = incl - x + wpre + bsums[blockIdx.x];
    if (idx < n) {
        counts[idx] = excl;
        cursor[idx] = excl;
    }
}

// ---------- Phase 3: scatter (edge, src) pairs grouped by dst (2 edges/thread) ----------
__global__ void __launch_bounds__(256) scatter_edges(
    const int* __restrict__ eidx, int* __restrict__ cursor,
    int2* __restrict__ pairs, int n_edges)
{
    int t = blockIdx.x * blockDim.x + threadIdx.x;
    int e0 = 2 * t;
    if (e0 >= n_edges) return;
    if (e0 + 1 < n_edges) {
        int4 q = *(const int4*)(eidx + 4 * (size_t)t);   // (src0,dst0,src1,dst1)
        int pos0 = atomicAdd(cursor + q.y, 1);
        pairs[pos0] = make_int2(e0, q.x);
        int pos1 = atomicAdd(cursor + q.w, 1);
        pairs[pos1] = make_int2(e0 + 1, q.z);
    } else {
        int src = eidx[2 * e0];
        int dst = eidx[2 * e0 + 1];
        int pos = atomicAdd(cursor + dst, 1);
        pairs[pos] = make_int2(e0, src);
    }
}

// ---------- Phase 4: gather — one wave per node, lane&31 = channel ----------
struct EdgeRegs {
    vf4  y;
    float h0, ha, hb, hc;
    float w0, w1, w2, w3, w4;
};

__global__ void __launch_bounds__(256) gather_nodes(
    const float* __restrict__ nf,
    const float* __restrict__ ang,
    const float* __restrict__ w,
    const int*  __restrict__ offsets,
    const int2* __restrict__ pairs,
    float* __restrict__ out,
    int n_nodes)
{
    const float INV_SQRT3 = 0.5773502691896258f;
    const float INV_SQRT2 = 0.7071067811865476f;

    int gtid = blockIdx.x * blockDim.x + threadIdx.x;
    int node = gtid >> 6;          // one 64-lane wave per node
    if (node >= n_nodes) return;
    int lane = threadIdx.x & 63;
    int c    = lane & 31;          // channel
    int half = lane >> 5;          // two contiguous edge sub-ranges per wave

    int start = offsets[node];
    int end   = offsets[node + 1];
    int cnt   = end - start;
    int mid   = start + ((cnt + 1) >> 1);
    int lo    = half ? mid : start;
    int hi    = half ? end : mid;

    // issue all 10 loads of one edge into named registers
    auto load_edge = [&](EdgeRegs& E, int e, int s) {
        const float* wp = w + (size_t)e * W_DIM + c;
        E.w0 = __builtin_nontemporal_load(wp);
        E.w1 = __builtin_nontemporal_load(wp + 32);
        E.w2 = __builtin_nontemporal_load(wp + 64);
        E.w3 = __builtin_nontemporal_load(wp + 96);
        E.w4 = __builtin_nontemporal_load(wp + 128);
        E.y  = __builtin_nontemporal_load((const vf4*)(ang + 4 * (size_t)e));
        const float* hp = nf + (size_t)s * IN_DIM + c;
        E.h0 = hp[0];
        E.ha = hp[32];
        E.hb = hp[64];
        E.hc = hp[96];
    };

    float aA0 = 0.f, aA1 = 0.f, aA2 = 0.f, aA3 = 0.f, aA4 = 0.f, aA5 = 0.f, aA6 = 0.f;
    float aB0 = 0.f, aB1 = 0.f, aB2 = 0.f, aB3 = 0.f, aB4 = 0.f, aB5 = 0.f, aB6 = 0.f;

    #define COMPUTE(E, s0, s1, s2, s3, s4, s5, s6)                           \
        do {                                                                 \
            float dot = E.ha * E.y[1] + E.hb * E.y[2] + E.hc * E.y[3];       \
            s0 += E.w0 * E.h0 * E.y[0] + E.w3 * (INV_SQRT3 * dot);           \
            s1 += E.w1 * E.h0 * E.y[1] + E.w2 * E.ha * E.y[0];               \
            s2 += E.w1 * E.h0 * E.y[2] + E.w2 * E.hb * E.y[0];               \
            s3 += E.w1 * E.h0 * E.y[3] + E.w2 * E.hc * E.y[0];               \
            float w4s = E.w4 * INV_SQRT2;                                    \
            s4 += w4s * (E.hb * E.y[3] - E.hc * E.y[2]);                     \
            s5 += w4s * (E.hc * E.y[1] - E.ha * E.y[3]);                     \
            s6 += w4s * (E.ha * E.y[2] - E.hb * E.y[1]);                     \
        } while (0)

    int i = lo;
    if (i + 1 < hi) {
        // prime: 2 edges in flight
        vi4 q = *(const vi4*)(pairs + i);          // pairs[i], pairs[i+1] (8B-aligned dwordx4)
        EdgeRegs E0, E1;
        load_edge(E0, q.x, q.y);
        load_edge(E1, q.z, q.w);
        i += 2;
        for (; i + 1 < hi; i += 2) {
            vi4 qn = *(const vi4*)(pairs + i);
            EdgeRegs N0, N1;
            load_edge(N0, qn.x, qn.y);             // next batch's loads issue...
            load_edge(N1, qn.z, qn.w);
            COMPUTE(E0, aA0, aA1, aA2, aA3, aA4, aA5, aA6);   // ...while current computes
            COMPUTE(E1, aB0, aB1, aB2, aB3, aB4, aB5, aB6);
            E0 = N0;
            E1 = N1;
        }
        COMPUTE(E0, aA0, aA1, aA2, aA3, aA4, aA5, aA6);
        COMPUTE(E1, aB0, aB1, aB2, aB3, aB4, aB5, aB6);
    }
    if (i < hi) {
        int2 p = pairs[i];
        EdgeRegs E;
        load_edge(E, p.x, p.y);
        COMPUTE(E, aA0, aA1, aA2, aA3, aA4, aA5, aA6);
    }
    #undef COMPUTE

    float a0 = aA0 + aB0, a1 = aA1 + aB1, a2 = aA2 + aB2, a3 = aA3 + aB3;
    float a4 = aA4 + aB4, a5 = aA5 + aB5, a6 = aA6 + aB6;

    // combine the two half-wave edge streams
    a0 += __shfl_xor(a0, 32);
    a1 += __shfl_xor(a1, 32);
    a2 += __shfl_xor(a2, 32);
    a3 += __shfl_xor(a3, 32);
    a4 += __shfl_xor(a4, 32);
    a5 += __shfl_xor(a5, 32);
    a6 += __shfl_xor(a6, 32);

    if (half == 0) {
        float* op = out + (size_t)node * OUT_DIM + c;
        __builtin_nontemporal_store(a0, op);
        __builtin_nontemporal_store(a1, op + 32);
        __builtin_nontemporal_store(a2, op + 64);
        __builtin_nontemporal_store(a3, op + 96);
        __builtin_nontemporal_store(a4, op + 128);
        __builtin_nontemporal_store(a5, op + 160);
        __builtin_nontemporal_store(a6, op + 192);
    }
}

// ---------- Fallback (R1 atomic path) if ws too small ----------
__global__ void __launch_bounds__(256) conv_tp_edges_atomic(
    const float* __restrict__ nf,
    const float* __restrict__ ang,
    const int*   __restrict__ eidx,
    const float* __restrict__ w,
    float* __restrict__ out,
    int n_edges)
{
    const float INV_SQRT3 = 0.5773502691896258f;
    const float INV_SQRT2 = 0.7071067811865476f;

    int tid = blockIdx.x * blockDim.x + threadIdx.x;
    int e = tid >> 3;
    int t = tid & 7;
    if (e >= n_edges) return;

    int src = eidx[2 * e];
    int dst = eidx[2 * e + 1];
    float4 y = *(const float4*)(ang + 4 * (size_t)e);

    const float* hp = nf + (size_t)src * IN_DIM + 4 * t;
    float4 h0  = *(const float4*)(hp);
    float4 h1a = *(const float4*)(hp + 32);
    float4 h1b = *(const float4*)(hp + 64);
    float4 h1c = *(const float4*)(hp + 96);

    const float* wp = w + (size_t)e * W_DIM + 4 * t;
    float4 w0 = *(const float4*)(wp);
    float4 w1 = *(const float4*)(wp + 32);
    float4 w2 = *(const float4*)(wp + 64);
    float4 w3 = *(const float4*)(wp + 96);
    float4 w4 = *(const float4*)(wp + 128);

    float* op = out + (size_t)dst * OUT_DIM + 4 * t;

    #pragma unroll
    for (int i = 0; i < 4; ++i) {
        float h0c = elem(h0, i), ha = elem(h1a, i), hb = elem(h1b, i), hc = elem(h1c, i);
        float dot = ha * y.y + hb * y.z + hc * y.w;
        atomicAdd(op + i, elem(w0, i) * h0c * y.x + elem(w3, i) * (INV_SQRT3 * dot));
        float w1c = elem(w1, i), w2c = elem(w2, i);
        atomicAdd(op + 32 + i, w1c * h0c * y.y + w2c * ha * y.x);
        atomicAdd(op + 64 + i, w1c * h0c * y.z + w2c * hb * y.x);
        atomicAdd(op + 96 + i, w1c * h0c * y.w + w2c * hc * y.x);
        float w4c = elem(w4, i) * INV_SQRT2;
        atomicAdd(op + 128 + i, w4c * (hb * y.w - hc * y.z));
        atomicAdd(op + 160 + i, w4c * (hc * y.y - ha * y.w));
        atomicAdd(op + 192 + i, w4c * (ha * y.z - hb * y.y));
    }
}

extern "C" void kernel_launch(void* const* d_in, const int* in_sizes, int n_in,
                              void* d_out, int out_size, void* d_ws, size_t ws_size,
                              hipStream_t stream) {
    const float* nf   = (const float*)d_in[0];
    const float* ang  = (const float*)d_in[1];
    const int*   eidx = (const int*)d_in[2];
    const float* w    = (const float*)d_in[3];
    float* out = (float*)d_out;

    int n_edges = in_sizes[2] / 2;
    int n_nodes = out_size / OUT_DIM;
    int nb = (n_nodes + 255) / 256;   // scan blocks

    // ws layout (ints): counts/offsets[n_nodes+1] | cursor[n_nodes] | bsums[nb]
    //                   | pad | pairs int2[n_edges]
    size_t off_counts = 0;
    size_t off_cursor = off_counts + (size_t)(n_nodes + 1);
    size_t off_bsums  = off_cursor + (size_t)n_nodes;
    size_t off_pairs  = (off_bsums + (size_t)nb + 1) & ~(size_t)1;  // 8B align
    size_t ints_needed = off_pairs + 2 * (size_t)n_edges;
    size_t bytes_needed = ints_needed * sizeof(int);

    if (ws_size < bytes_needed) {
        // fallback: atomic path (correct, slower)
        hipMemsetAsync(d_out, 0, (size_t)out_size * sizeof(float), stream);
        int threads_total = n_edges * 8;
        int grid = (threads_total + 255) / 256;
        conv_tp_edges_atomic<<<grid, 256, 0, stream>>>(nf, ang, eidx, w, out, n_edges);
        return;
    }

    int* counts  = (int*)d_ws + off_counts;
    int* cursor  = (int*)d_ws + off_cursor;
    int* bsums   = (int*)d_ws + off_bsums;
    int2* pairs  = (int2*)((int*)d_ws + off_pairs);

    hipMemsetAsync(counts, 0, (size_t)(n_nodes + 1) * sizeof(int), stream);

    int half_e = (n_edges + 1) / 2;
    int grid_e2 = (half_e + 255) / 256;
    hist_dst<<<grid_e2, 256, 0, stream>>>(eidx, counts, n_edges);
    block_sums<<<nb, 256, 0, stream>>>(counts, bsums, n_nodes);
    scan_block_sums<<<1, 256, 0, stream>>>(bsums, counts + n_nodes, nb);
    scan_final<<<nb, 256, 0, stream>>>(counts, cursor, bsums, n_nodes);
    scatter_edges<<<grid_e2, 256, 0, stream>>>(eidx, cursor, pairs, n_edges);

    int threads_total = n_nodes * 64;           // one wave per node
    int grid_g = (threads_total + 255) / 256;
    gather_nodes<<<grid_g, 256, 0, stream>>>(nf, ang, w, counts, pairs, out, n_nodes);
}